// Round 1
// baseline (78.410 us; speedup 1.0000x reference)
//
#include <hip/hip_runtime.h>

// SmileResampler: out[b,bh,h,w] = lerp over band axis of x at
// iy = clip(bh + clip(ws[b,bh,w],-2,2), 0, 127) * (128/127) - 0.5
// Shapes: x (4,128,256,256) f32, ws (4,128,256) f32, out same as x.

#define BH_ 128
#define H_  256
#define W_  256

__global__ __launch_bounds__(256) void smile_kernel(
    const float* __restrict__ x,
    const float* __restrict__ ws,
    float* __restrict__ out,
    int total4)
{
    int idx4 = blockIdx.x * blockDim.x + threadIdx.x;
    if (idx4 >= total4) return;

    // idx4 -> (b, bh, h, w0) with w0 = 4*w4
    const int w4 = idx4 & (W_ / 4 - 1);      // 0..63
    int tmp = idx4 >> 6;
    const int h  = tmp & (H_ - 1);           // 0..255
    tmp >>= 8;
    const int bh = tmp & (BH_ - 1);          // 0..127
    const int b  = tmp >> 7;
    const int w0 = w4 * 4;

    const float4 s4 = *reinterpret_cast<const float4*>(
        &ws[(b * BH_ + bh) * W_ + w0]);

    const float scale = (float)(128.0 / 127.0);
    const float bandf = (float)bh;
    // x index = ((b*BH + band)*H + h)*W + w ; band term added per gather
    const int xbase = b * (BH_ * H_ * W_) + h * W_ + w0;

    float sv[4] = {s4.x, s4.y, s4.z, s4.w};
    float ov[4];

#pragma unroll
    for (int j = 0; j < 4; ++j) {
        float s       = fminf(fmaxf(sv[j], -2.0f), 2.0f);
        float shifted = fminf(fmaxf(bandf + s, 0.0f), 127.0f);
        float iy      = shifted * scale - 0.5f;
        float i0f     = floorf(iy);
        float frac    = iy - i0f;
        int   i0      = (int)i0f;
        int   i0c     = min(max(i0, 0), BH_ - 1);
        int   i1c     = min(max(i0 + 1, 0), BH_ - 1);
        float x0 = x[xbase + i0c * (H_ * W_) + j];
        float x1 = x[xbase + i1c * (H_ * W_) + j];
        ov[j] = x0 * (1.0f - frac) + x1 * frac;
    }

    float4 o = make_float4(ov[0], ov[1], ov[2], ov[3]);
    *reinterpret_cast<float4*>(&out[(size_t)idx4 * 4]) = o;
}

extern "C" void kernel_launch(void* const* d_in, const int* in_sizes, int n_in,
                              void* d_out, int out_size, void* d_ws, size_t ws_size,
                              hipStream_t stream) {
    const float* x  = (const float*)d_in[0];
    const float* ws = (const float*)d_in[1];
    float* out = (float*)d_out;

    const int total  = out_size;          // 4*128*256*256 = 33554432
    const int total4 = total / 4;         // 8388608
    const int block  = 256;
    const int grid   = (total4 + block - 1) / block;

    smile_kernel<<<grid, block, 0, stream>>>(x, ws, out, total4);
}

// Round 2
// 67.288 us; speedup vs baseline: 1.1653x; 1.1653x over previous
//
#include <hip/hip_runtime.h>

// SmileResampler: out[b,bh,h,w] = lerp over band axis of x at
// iy = clip(bh + clip(ws[b,bh,w],-2,2), 0, 127) * (128/127) - 0.5
// Shapes: x (4,128,256,256) f32, ws (4,128,256) f32, out same as x.
//
// Layout: one wave (64 lanes) per (b,bh,h) row; lane handles w = lane + 64*j,
// j=0..3. All global accesses (ws load, 8 x gathers, 4 out stores) are
// unit-stride coalesced dwords across the wave — no 16B-strided gathers.

#define BH_ 128
#define H_  256
#define W_  256

__global__ __launch_bounds__(256) void smile_kernel(
    const float* __restrict__ x,
    const float* __restrict__ ws,
    float* __restrict__ out,
    int nrows)
{
    const int gid  = blockIdx.x * blockDim.x + threadIdx.x;
    const int lane = gid & 63;
    const int row  = gid >> 6;              // (b*BH + bh)*H + h
    if (row >= nrows) return;

    const int h  = row & (H_ - 1);
    const int bh = (row >> 8) & (BH_ - 1);
    const int b  = row >> 15;               // row / (BH*H)

    const float* __restrict__ wsrow = ws + ((b * BH_ + bh) * W_);
    // x[b, band, h, w] = xbh[band*65536 + w]
    const float* __restrict__ xbh = x + ((size_t)b * (BH_ * H_ * W_)) + h * W_;
    float* __restrict__ outrow = out + (size_t)row * W_;

    const float scale = (float)(128.0 / 127.0);
    const float bandf = (float)bh;

    float s[4];
#pragma unroll
    for (int j = 0; j < 4; ++j)
        s[j] = wsrow[lane + 64 * j];

    float x0[4], x1[4], frac[4];
#pragma unroll
    for (int j = 0; j < 4; ++j) {
        const int w = lane + 64 * j;
        float sc      = fminf(fmaxf(s[j], -2.0f), 2.0f);
        float shifted = fminf(fmaxf(bandf + sc, 0.0f), 127.0f);
        float iy      = fmaf(shifted, scale, -0.5f);
        float i0f     = floorf(iy);
        frac[j]       = iy - i0f;
        int   i0      = (int)i0f;
        int   i0c     = min(max(i0, 0), BH_ - 1);
        int   i1c     = min(max(i0 + 1, 0), BH_ - 1);
        x0[j] = xbh[i0c * (H_ * W_) + w];
        x1[j] = xbh[i1c * (H_ * W_) + w];
    }

#pragma unroll
    for (int j = 0; j < 4; ++j) {
        const int w = lane + 64 * j;
        outrow[w] = fmaf(frac[j], x1[j] - x0[j], x0[j]);
    }
}

extern "C" void kernel_launch(void* const* d_in, const int* in_sizes, int n_in,
                              void* d_out, int out_size, void* d_ws, size_t ws_size,
                              hipStream_t stream) {
    const float* x  = (const float*)d_in[0];
    const float* ws = (const float*)d_in[1];
    float* out = (float*)d_out;

    const int nrows  = 4 * BH_ * H_;        // 131072 rows of 256 w
    const int block  = 256;                 // 4 waves = 4 rows per block
    const int grid   = nrows / (block / 64);

    smile_kernel<<<grid, block, 0, stream>>>(x, ws, out, nrows);
}

// Round 3
// 55.254 us; speedup vs baseline: 1.4191x; 1.2178x over previous
//
#include <hip/hip_runtime.h>

// SmileResampler: out[b,bh,h,w] = lerp over band axis of x at
// iy = clip(bh + clip(ws[b,bh,w],-2,2), 0, 127) * (128/127) - 0.5
// Shapes: x (4,128,256,256) f32, ws (4,128,256) f32, out same as x.
//
// Structure: block = (b, h, 16-band tile). Stage the 22 candidate band-rows
// (tile + 3-halo each side; shift is clipped to ±2 so i0c/i1c are within
// [bh-3, bh+2]) into LDS with unit-stride float4 loads, then gather from LDS
// (per-lane band index is free there; bank = w%32 regardless of band slot ->
// 2-way aliasing only). All global accesses are unit-stride coalesced.

#define BH_ 128
#define H_  256
#define W_  256
#define TB   16          // output bands per block
#define NLDS (TB + 6)    // staged band rows (3-halo each side)

__global__ __launch_bounds__(256) void smile_kernel(
    const float* __restrict__ x,
    const float* __restrict__ ws,
    float* __restrict__ out)
{
    __shared__ float tile[NLDS][W_];   // 22 * 1 KiB = 22.5 KiB

    const int t = threadIdx.x;
    int bid = blockIdx.x;
    const int tileI = bid & 7;         // 128/TB = 8 tiles
    bid >>= 3;
    const int h = bid & (H_ - 1);
    const int b = bid >> 8;
    const int bh0 = tileI * TB;

    // ---- stage x[b, bh0-3 .. bh0+TB+2 (clamped), h, :] into LDS ----
    const float* __restrict__ xsrc = x + (size_t)b * (BH_ * H_ * W_) + h * W_;
    for (int item = t; item < NLDS * (W_ / 4); item += 256) {
        const int i = item >> 6;           // LDS row
        const int q = item & 63;           // float4 index within row
        const int band = min(max(bh0 - 3 + i, 0), BH_ - 1);
        const float4 v = *reinterpret_cast<const float4*>(
            &xsrc[(size_t)band * (H_ * W_) + q * 4]);
        *reinterpret_cast<float4*>(&tile[i][q * 4]) = v;
    }
    __syncthreads();

    // ---- compute: r = band within tile, w = t ----
    const float scale = (float)(128.0 / 127.0);
    const int w = t;
    const float* __restrict__ wsb = ws + (size_t)(b * BH_) * W_;
    float* __restrict__ outb =
        out + (((size_t)b * BH_ + bh0) * H_ + h) * W_;

#pragma unroll 4
    for (int r = 0; r < TB; ++r) {
        const int bh = bh0 + r;
        float s       = wsb[bh * W_ + w];
        float sc      = fminf(fmaxf(s, -2.0f), 2.0f);
        float shifted = fminf(fmaxf((float)bh + sc, 0.0f), (float)(BH_ - 1));
        float iy      = shifted * scale - 0.5f;
        float i0f     = floorf(iy);
        float frac    = iy - i0f;
        int   i0      = (int)i0f;
        int   i0c     = min(max(i0, 0), BH_ - 1);
        int   i1c     = min(i0 + 1, BH_ - 1);   // i0 >= -1 so i0+1 >= 0
        float x0 = tile[i0c - bh0 + 3][w];
        float x1 = tile[i1c - bh0 + 3][w];
        outb[(size_t)r * (H_ * W_) + w] = x0 * (1.0f - frac) + x1 * frac;
    }
}

extern "C" void kernel_launch(void* const* d_in, const int* in_sizes, int n_in,
                              void* d_out, int out_size, void* d_ws, size_t ws_size,
                              hipStream_t stream) {
    const float* x  = (const float*)d_in[0];
    const float* ws = (const float*)d_in[1];
    float* out = (float*)d_out;

    const int grid = 4 * H_ * (BH_ / TB);   // b * h * tiles = 8192
    smile_kernel<<<grid, 256, 0, stream>>>(x, ws, out);
}

// Round 4
// 50.647 us; speedup vs baseline: 1.5482x; 1.0910x over previous
//
#include <hip/hip_runtime.h>

// SmileResampler: out[b,bh,h,w] = lerp over band axis of x at
// iy = clip(bh + clip(ws[b,bh,w],-2,2), 0, 127) * (128/127) - 0.5
// Shapes: x (4,128,256,256) f32, ws (4,128,256) f32, out same as x.
//
// Block = (b, h, 16-band tile). Stage 22 candidate band-rows (tile + halo;
// i0c in [bh-3,bh+2], i1c up to bh+3) into LDS via async global_load_lds
// (1 KiB per wave-instruction, no VGPR round-trip). Compute phase: all 16
// ws loads hoisted/in-flight, then fully-unrolled lerp from LDS.
// All global accesses unit-stride coalesced; LDS reads 2-way-alias free.

#define BH_ 128
#define H_  256
#define W_  256
#define TB   16          // output bands per block
#define NLDS (TB + 6)    // staged band rows (3-halo each side)

__global__ __launch_bounds__(256) void smile_kernel(
    const float* __restrict__ x,
    const float* __restrict__ ws,
    float* __restrict__ out)
{
    __shared__ float tile[NLDS][W_];   // 22 * 1 KiB = 22.5 KiB

    const int t = threadIdx.x;
    int bid = blockIdx.x;
    const int tileI = bid & 7;         // 128/TB = 8 tiles
    bid >>= 3;
    const int h = bid & (H_ - 1);
    const int b = bid >> 8;
    const int bh0 = tileI * TB;

    // ---- async stage: one global_load_lds (64 lanes x 16B = 1 KiB) per row ----
    const float* __restrict__ xsrc = x + (size_t)b * (BH_ * H_ * W_) + h * W_;
    const int wave = t >> 6;
    const int lane = t & 63;
    for (int i = wave; i < NLDS; i += 4) {
        const int band = min(max(bh0 - 3 + i, 0), BH_ - 1);
        const float* gp = xsrc + (size_t)band * (H_ * W_) + lane * 4;
        __builtin_amdgcn_global_load_lds(
            (const __attribute__((address_space(1))) void*)gp,
            (__attribute__((address_space(3))) void*)&tile[i][0],
            16, 0, 0);
    }
    __syncthreads();   // compiler drains vmcnt before s_barrier

    // ---- compute: thread t owns column w = t for all 16 bands ----
    const float scale = (float)(128.0 / 127.0);
    const int w = t;
    const float* __restrict__ wsb = ws + (size_t)(b * BH_ + bh0) * W_ + w;
    float* __restrict__ outb =
        out + (((size_t)b * BH_ + bh0) * H_ + h) * W_ + w;

    float s[TB];
#pragma unroll
    for (int r = 0; r < TB; ++r)
        s[r] = wsb[r * W_];            // 16 independent loads in flight

#pragma unroll
    for (int r = 0; r < TB; ++r) {
        const int bh = bh0 + r;
        float sc      = fminf(fmaxf(s[r], -2.0f), 2.0f);
        float shifted = fminf(fmaxf((float)bh + sc, 0.0f), (float)(BH_ - 1));
        float iy      = fmaf(shifted, scale, -0.5f);
        float i0f     = floorf(iy);
        float frac    = iy - i0f;
        int   i0      = (int)i0f;
        int   r0      = min(max(i0, 0), BH_ - 1) - bh0 + 3;
        int   r1      = min(i0 + 1, BH_ - 1) - bh0 + 3;
        float x0 = tile[r0][w];
        float x1 = tile[r1][w];
        outb[(size_t)r * (H_ * W_)] = fmaf(frac, x1 - x0, x0);
    }
}

extern "C" void kernel_launch(void* const* d_in, const int* in_sizes, int n_in,
                              void* d_out, int out_size, void* d_ws, size_t ws_size,
                              hipStream_t stream) {
    const float* x  = (const float*)d_in[0];
    const float* ws = (const float*)d_in[1];
    float* out = (float*)d_out;

    const int grid = 4 * H_ * (BH_ / TB);   // b * h * tiles = 8192
    smile_kernel<<<grid, 256, 0, stream>>>(x, ws, out);
}

// Round 5
// 48.925 us; speedup vs baseline: 1.6027x; 1.0352x over previous
//
#include <hip/hip_runtime.h>

// SmileResampler: out[b,bh,h,w] = lerp over band axis of x at
// iy = clip(bh + clip(ws[b,bh,w],-2,2), 0, 127) * (128/127) - 0.5
// Shapes: x (4,128,256,256) f32, ws (4,128,256) f32, out same as x.
//
// Block = (b, h, 32-band tile), 512 threads (8 waves). Stage 38 candidate
// band-rows (tile + 3-halo) into LDS via async global_load_lds (16 B/lane,
// 1 KiB per wave-instruction). ws loads issued BEFORE the barrier so their
// latency overlaps the staging drain. Thread t owns column w = t&255 and
// bands [bh0 + (t>>8)*16 .. +16). LDS 38 KiB -> 4 blocks/CU -> 32 waves/CU
// (100% occupancy). All global accesses unit-stride coalesced.

#define BH_ 128
#define H_  256
#define W_  256
#define TB   32          // output bands per block
#define NLDS (TB + 6)    // staged band rows (3-halo each side)
#define RPT  16          // bands per thread (TB / 2 half-groups)

__global__ __launch_bounds__(512) void smile_kernel(
    const float* __restrict__ x,
    const float* __restrict__ ws,
    float* __restrict__ out)
{
    __shared__ float tile[NLDS][W_];   // 38 KiB

    const int t = threadIdx.x;
    int bid = blockIdx.x;
    const int tileI = bid & 3;         // 128/TB = 4 tiles
    bid >>= 2;
    const int h = bid & (H_ - 1);
    const int b = bid >> 8;
    const int bh0 = tileI * TB;

    const int wave = t >> 6;           // 0..7
    const int lane = t & 63;
    const int w  = t & (W_ - 1);       // column this thread owns
    const int hr = t >> 8;             // 0/1: which 16-band half

    // ---- async stage: one global_load_lds (64 lanes x 16B = 1 KiB) per row ----
    const float* __restrict__ xsrc = x + (size_t)b * (BH_ * H_ * W_) + h * W_;
    for (int i = wave; i < NLDS; i += 8) {
        const int band = min(max(bh0 - 3 + i, 0), BH_ - 1);
        const float* gp = xsrc + (size_t)band * (H_ * W_) + lane * 4;
        __builtin_amdgcn_global_load_lds(
            (const __attribute__((address_space(1))) void*)gp,
            (__attribute__((address_space(3))) void*)&tile[i][0],
            16, 0, 0);
    }

    // ---- ws loads issued pre-barrier: latency overlaps the staging drain ----
    const int bhbase = bh0 + hr * RPT;
    const float* __restrict__ wsb = ws + (size_t)(b * BH_ + bhbase) * W_ + w;
    float s[RPT];
#pragma unroll
    for (int r = 0; r < RPT; ++r)
        s[r] = wsb[r * W_];

    __syncthreads();   // drains vmcnt (staging + ws) before barrier

    // ---- compute ----
    const float scale = (float)(128.0 / 127.0);
    float* __restrict__ outb =
        out + (((size_t)b * BH_ + bhbase) * H_ + h) * W_ + w;

#pragma unroll
    for (int r = 0; r < RPT; ++r) {
        const int bh = bhbase + r;
        float sc      = fminf(fmaxf(s[r], -2.0f), 2.0f);
        float shifted = fminf(fmaxf((float)bh + sc, 0.0f), (float)(BH_ - 1));
        float iy      = fmaf(shifted, scale, -0.5f);
        float i0f     = floorf(iy);
        float frac    = iy - i0f;
        int   i0      = (int)i0f;
        int   r0      = min(max(i0, 0), BH_ - 1) - bh0 + 3;
        int   r1      = min(i0 + 1, BH_ - 1) - bh0 + 3;
        float x0 = tile[r0][w];
        float x1 = tile[r1][w];
        outb[(size_t)r * (H_ * W_)] = fmaf(frac, x1 - x0, x0);
    }
}

extern "C" void kernel_launch(void* const* d_in, const int* in_sizes, int n_in,
                              void* d_out, int out_size, void* d_ws, size_t ws_size,
                              hipStream_t stream) {
    const float* x  = (const float*)d_in[0];
    const float* ws = (const float*)d_in[1];
    float* out = (float*)d_out;

    const int grid = 4 * H_ * (BH_ / TB);   // b * h * tiles = 4096
    smile_kernel<<<grid, 512, 0, stream>>>(x, ws, out);
}